// Round 3
// baseline (486.890 us; speedup 1.0000x reference)
//
#include <hip/hip_runtime.h>

// Child-Sum Tree-LSTM, 16 trees x branch4 x depth8, HIDDEN=IN_DIM=128.
// Strategy: per-level fused MFMA kernels (bf16 inputs, f32 accum).
// ws layout: h_all (bf16, 349520x128), c_all (f32, 349520x128),
//            Wcat (384x256 bf16: [Wix|Wih; Wox|Woh; Wux|Wuh]), Wfx, Wfh bf16.

#define HID 128

typedef unsigned short u16;
typedef __attribute__((ext_vector_type(8))) short short8;
typedef __attribute__((ext_vector_type(4))) float floatx4;

__device__ __forceinline__ float bf2f(u16 u) {
  union { unsigned int u; float f; } v; v.u = ((unsigned int)u) << 16; return v.f;
}
__device__ __forceinline__ u16 f2bf(float f) {
  union { float f; unsigned int u; } v; v.f = f;
  unsigned int r = v.u + 0x7FFFu + ((v.u >> 16) & 1u);
  return (u16)(r >> 16);
}
__device__ __forceinline__ float sigm(float x) { return 1.0f / (1.0f + __expf(-x)); }
__device__ __forceinline__ float tanh_fast(float x) {
  float ax = fabsf(x);
  float e = __expf(-2.0f * ax);
  float t = (1.0f - e) / (1.0f + e);
  return copysignf(t, x);
}

__global__ void prep_weights(const float* __restrict__ Wix, const float* __restrict__ Wih,
                             const float* __restrict__ Wfx, const float* __restrict__ Wfh,
                             const float* __restrict__ Wox, const float* __restrict__ Woh,
                             const float* __restrict__ Wux, const float* __restrict__ Wuh,
                             u16* __restrict__ Wcat, u16* __restrict__ Wfxb, u16* __restrict__ Wfhb)
{
  int t = blockIdx.x * 256 + threadIdx.x;
  if (t < 98304) {                 // Wcat: 384 rows x 256 k
    int nrow = t >> 8, k = t & 255;
    int gate = nrow >> 7, r = nrow & 127;
    float v;
    if (k < 128) {
      const float* W = (gate == 0) ? Wix : (gate == 1) ? Wox : Wux;
      v = W[r * 128 + k];
    } else {
      const float* W = (gate == 0) ? Wih : (gate == 1) ? Woh : Wuh;
      v = W[r * 128 + (k - 128)];
    }
    Wcat[t] = f2bf(v);
  } else if (t < 98304 + 16384) {
    int i = t - 98304;
    Wfxb[i] = f2bf(Wfx[i]);
  } else if (t < 98304 + 32768) {
    int i = t - 98304 - 16384;
    Wfhb[i] = f2bf(Wfh[i]);
  }
}

// Per-level kernel. Block = 256 threads (4 waves), 32 parents (128 children).
// LEAF=1: no children (level 7): only i/o/u GEMM (K=128) + elementwise.
// LEAF=0: fx-GEMM -> LDS, h_sum -> LDS (swizzled bf16), fh-GEMM in acc,
//         f/fc in-lane reduce -> LDS, then K=256 GEMM [x|h_sum]@Wcat^T, epilogue.
template <int LEAF>
__global__ __launch_bounds__(256, 2)
void level_kernel(const float* __restrict__ embeds,
                  const u16* __restrict__ Wcat,
                  const u16* __restrict__ Wfxb,
                  const u16* __restrict__ Wfhb,
                  const float* __restrict__ bix, const float* __restrict__ bfx,
                  const float* __restrict__ box, const float* __restrict__ bux,
                  u16* __restrict__ h_all, float* __restrict__ c_all,
                  int n, int node_off, int child_off)
{
  extern __shared__ char smem[];
  u16*   s_hsum = (u16*)smem;                    // 32x128 bf16, XOR-swizzled (8 KB)
  float* s_fx   = (float*)(smem + 8192);         // 32x128 f32 (16 KB)
  float* s_fc   = (float*)(smem + 8192 + 16384); // 32x128 f32 (16 KB)

  const int tid  = threadIdx.x;
  const int wave = tid >> 6;
  const int lane = tid & 63;
  const int lg   = lane >> 4;   // lane group (k-offset group / acc row group)
  const int ln   = lane & 15;   // row (A) / col (B,C)
  const int pbase = blockIdx.x * 32;

  // ---- hoisted x A-fragments: rows = parent m*16+ln, k = kt*32+lg*8 ----
  short8 a_x[2][4];
  {
    const float* xb = embeds + (size_t)(node_off + pbase) * HID;
#pragma unroll
    for (int m = 0; m < 2; ++m)
#pragma unroll
      for (int kt = 0; kt < 4; ++kt) {
        const float* p = xb + (size_t)(m * 16 + ln) * HID + kt * 32 + lg * 8;
        float4 f0 = *(const float4*)p;
        float4 f1 = *(const float4*)(p + 4);
        short8 s;
        s[0] = (short)f2bf(f0.x); s[1] = (short)f2bf(f0.y);
        s[2] = (short)f2bf(f0.z); s[3] = (short)f2bf(f0.w);
        s[4] = (short)f2bf(f1.x); s[5] = (short)f2bf(f1.y);
        s[6] = (short)f2bf(f1.z); s[7] = (short)f2bf(f1.w);
        a_x[m][kt] = s;
      }
  }

  if constexpr (LEAF == 0) {
    // ---- fx GEMM: 32 parents x 128 cols; wave owns N-tiles {2w, 2w+1} ----
    floatx4 acc_fx[2][2] = {};
#pragma unroll
    for (int kt = 0; kt < 4; ++kt)
#pragma unroll
      for (int ntl = 0; ntl < 2; ++ntl) {
        int nt = wave * 2 + ntl;
        short8 b = *(const short8*)(Wfxb + (size_t)(nt * 16 + ln) * HID + kt * 32 + lg * 8);
#pragma unroll
        for (int m = 0; m < 2; ++m)
          acc_fx[m][ntl] = __builtin_amdgcn_mfma_f32_16x16x32_bf16(a_x[m][kt], b, acc_fx[m][ntl], 0, 0, 0);
      }
#pragma unroll
    for (int m = 0; m < 2; ++m)
#pragma unroll
      for (int ntl = 0; ntl < 2; ++ntl) {
        int col = (wave * 2 + ntl) * 16 + ln;
#pragma unroll
        for (int r = 0; r < 4; ++r) {
          int row = m * 16 + lg * 4 + r;
          s_fx[row * HID + col] = acc_fx[m][ntl][r];
        }
      }

    // ---- h_sum: thread -> parent p=tid>>3, 16 cols at (tid&7)*16 ----
    {
      int p = tid >> 3, cg = tid & 7;
      const u16* ch = h_all + (size_t)(child_off + 4 * (pbase + p)) * HID + cg * 16;
      float hs[16];
#pragma unroll
      for (int j = 0; j < 16; ++j) hs[j] = 0.f;
#pragma unroll
      for (int b = 0; b < 4; ++b) {
        short8 v0 = *(const short8*)(ch + (size_t)b * HID);
        short8 v1 = *(const short8*)(ch + (size_t)b * HID + 8);
#pragma unroll
        for (int j = 0; j < 8; ++j) {
          hs[j]     += bf2f((u16)v0[j]);
          hs[8 + j] += bf2f((u16)v1[j]);
        }
      }
      short8 o0, o1;
#pragma unroll
      for (int j = 0; j < 8; ++j) { o0[j] = (short)f2bf(hs[j]); o1[j] = (short)f2bf(hs[8 + j]); }
      unsigned sw = ((unsigned)(p & 7)) << 4;   // 16B XOR swizzle vs 256B row stride
      *(short8*)((char*)s_hsum + p * 256 + ((cg * 32) ^ sw))      = o0;
      *(short8*)((char*)s_hsum + p * 256 + ((cg * 32 + 16) ^ sw)) = o1;
    }

    // ---- fh GEMM: wave owns child rows [w*32, w*32+32), all 128 cols ----
    short8 a_h[2][4];
    {
      const u16* chb = h_all + (size_t)(child_off + 4 * pbase + wave * 32) * HID;
#pragma unroll
      for (int m = 0; m < 2; ++m)
#pragma unroll
        for (int kt = 0; kt < 4; ++kt)
          a_h[m][kt] = *(const short8*)(chb + (size_t)(m * 16 + ln) * HID + kt * 32 + lg * 8);
    }
    floatx4 acc_fh[2][8] = {};
#pragma unroll
    for (int kt = 0; kt < 4; ++kt)
#pragma unroll
      for (int nt = 0; nt < 8; ++nt) {
        short8 b = *(const short8*)(Wfhb + (size_t)(nt * 16 + ln) * HID + kt * 32 + lg * 8);
#pragma unroll
        for (int m = 0; m < 2; ++m)
          acc_fh[m][nt] = __builtin_amdgcn_mfma_f32_16x16x32_bf16(a_h[m][kt], b, acc_fh[m][nt], 0, 0, 0);
      }

    __syncthreads();

    // ---- f = sigm(fx + bfx + fh); fc_sum: 4 children live in this lane's 4 regs ----
#pragma unroll
    for (int m = 0; m < 2; ++m) {
      int ploc = wave * 8 + m * 4 + lg;
      const float* crow = c_all + (size_t)(child_off + 4 * pbase + wave * 32 + m * 16 + lg * 4) * HID;
#pragma unroll
      for (int nt = 0; nt < 8; ++nt) {
        int col = nt * 16 + ln;
        float fxv = s_fx[ploc * HID + col] + bfx[col];
        float fc = 0.f;
#pragma unroll
        for (int r = 0; r < 4; ++r) {
          float f = sigm(fxv + acc_fh[m][nt][r]);
          float cch = crow[(size_t)r * HID + col];
          fc += f * cch;
        }
        s_fc[ploc * HID + col] = fc;
      }
    }
    __syncthreads();
  }

  // ---- main GEMM: 32 parents x 384 (i|o|u), K=128 (leaf) / 256 (internal) ----
  // wave owns cols [w*32, w*32+32) WITHIN each gate -> epilogue is in-register.
  floatx4 acc[2][3][2] = {};
  constexpr int KT = LEAF ? 4 : 8;
#pragma unroll
  for (int kt = 0; kt < KT; ++kt) {
    short8 a[2];
    if (kt < 4) {
      a[0] = a_x[0][kt]; a[1] = a_x[1][kt];
    } else {
#pragma unroll
      for (int m = 0; m < 2; ++m) {
        int row = m * 16 + ln;
        unsigned sw = ((unsigned)(row & 7)) << 4;
        int kbyte = ((kt - 4) * 32 + lg * 8) * 2;
        a[m] = *(const short8*)((char*)s_hsum + row * 256 + (kbyte ^ sw));
      }
    }
#pragma unroll
    for (int g = 0; g < 3; ++g)
#pragma unroll
      for (int ntl = 0; ntl < 2; ++ntl) {
        int NT = g * 8 + wave * 2 + ntl;
        short8 b = *(const short8*)(Wcat + (size_t)(NT * 16 + ln) * 256 + kt * 32 + lg * 8);
#pragma unroll
        for (int m = 0; m < 2; ++m)
          acc[m][g][ntl] = __builtin_amdgcn_mfma_f32_16x16x32_bf16(a[m], b, acc[m][g][ntl], 0, 0, 0);
      }
  }

  // ---- epilogue: gates, c, h ----
#pragma unroll
  for (int m = 0; m < 2; ++m)
#pragma unroll
    for (int ntl = 0; ntl < 2; ++ntl) {
      int col = wave * 32 + ntl * 16 + ln;
      float bi = bix[col], bo = box[col], bu = bux[col];
#pragma unroll
      for (int r = 0; r < 4; ++r) {
        int row = m * 16 + lg * 4 + r;
        if (pbase + row < n) {
          float iv = sigm(acc[m][0][ntl][r] + bi);
          float ov = sigm(acc[m][1][ntl][r] + bo);
          float uv = tanh_fast(acc[m][2][ntl][r] + bu);
          float fc = (LEAF != 0) ? 0.f : s_fc[row * HID + col];
          float cv = iv * uv + fc;
          float hv = ov * tanh_fast(cv);
          size_t gidx = (size_t)(node_off + pbase + row) * HID + col;
          c_all[gidx] = cv;
          h_all[gidx] = f2bf(hv);
        }
      }
    }
}

__global__ void out_kernel(const u16* __restrict__ h_all, const float* __restrict__ Wout,
                           const float* __restrict__ bout, float* __restrict__ out)
{
  int t = threadIdx.x;
  if (t < 80) {                 // 16 roots x 5 labels
    int row = t / 5, lbl = t - row * 5;
    float s = bout[lbl];
    for (int k = 0; k < 128; ++k)
      s += bf2f(h_all[row * 128 + k]) * Wout[lbl * 128 + k];
    out[t] = s;
  }
}

extern "C" void kernel_launch(void* const* d_in, const int* in_sizes, int n_in,
                              void* d_out, int out_size, void* d_ws, size_t ws_size,
                              hipStream_t stream)
{
  const float* embeds = (const float*)d_in[0];
  const float* Wix = (const float*)d_in[1];
  const float* bix = (const float*)d_in[2];
  const float* Wih = (const float*)d_in[3];
  const float* Wfx = (const float*)d_in[4];
  const float* bfx = (const float*)d_in[5];
  const float* Wfh = (const float*)d_in[6];
  const float* Wox = (const float*)d_in[7];
  const float* box = (const float*)d_in[8];
  const float* Woh = (const float*)d_in[9];
  const float* Wux = (const float*)d_in[10];
  const float* bux = (const float*)d_in[11];
  const float* Wuh = (const float*)d_in[12];
  const float* Wout = (const float*)d_in[13];
  const float* bout = (const float*)d_in[14];

  static const int counts[8]  = {16, 64, 256, 1024, 4096, 16384, 65536, 262144};
  static const int offsets[9] = {0, 16, 80, 336, 1360, 5456, 21840, 87376, 349520};

  char* ws = (char*)d_ws;
  u16*   h_all = (u16*)ws;                                   // 89,477,120 B
  float* c_all = (float*)(ws + 89477120);                    // 178,954,240 B
  u16*   Wcat  = (u16*)(ws + 89477120 + 178954240);          // 384*256*2
  u16*   Wfxb  = Wcat + 384 * 256;
  u16*   Wfhb  = Wfxb + 128 * 128;

  prep_weights<<<512, 256, 0, stream>>>(Wix, Wih, Wfx, Wfh, Wox, Woh, Wux, Wuh,
                                        Wcat, Wfxb, Wfhb);

  // level 7 (leaves)
  level_kernel<1><<<262144 / 32, 256, 0, stream>>>(
      embeds, Wcat, Wfxb, Wfhb, bix, bfx, box, bux,
      h_all, c_all, 262144, 87376, 0);

  // levels 6..0 (internal)
  for (int l = 6; l >= 0; --l) {
    int n = counts[l];
    int grid = (n + 31) / 32;
    level_kernel<0><<<grid, 256, 40960, stream>>>(
        embeds, Wcat, Wfxb, Wfhb, bix, bfx, box, bux,
        h_all, c_all, n, offsets[l], offsets[l + 1]);
  }

  out_kernel<<<1, 128, 0, stream>>>(h_all, Wout, bout, (float*)d_out);
}

// Round 5
// 462.732 us; speedup vs baseline: 1.0522x; 1.0522x over previous
//
#include <hip/hip_runtime.h>

// Child-Sum Tree-LSTM, 16 trees x branch4 x depth8, HIDDEN=IN_DIM=128.
// Strategy: per-level fused MFMA kernels (bf16 inputs, f32 accum).
// R5: R3 structure exactly (launch_bounds(256,2) everywhere, leaf mask kept)
//     + rcp-based sigmoid/tanh only. (R4's launch_bounds(256,6) on the leaf
//     forced VGPR spills and is the prime suspect for graph-replay divergence.)

#define HID 128

typedef unsigned short u16;
typedef __attribute__((ext_vector_type(8))) short short8;
typedef __attribute__((ext_vector_type(4))) float floatx4;

__device__ __forceinline__ float bf2f(u16 u) {
  union { unsigned int u; float f; } v; v.u = ((unsigned int)u) << 16; return v.f;
}
__device__ __forceinline__ u16 f2bf(float f) {
  union { float f; unsigned int u; } v; v.f = f;
  unsigned int r = v.u + 0x7FFFu + ((v.u >> 16) & 1u);
  return (u16)(r >> 16);
}
// sigm(x) = 1/(1+e^-x) via v_rcp_f32 (no IEEE div sequence)
__device__ __forceinline__ float sigm(float x) {
  return __builtin_amdgcn_rcpf(1.0f + __expf(-x));
}
// tanh(|x|) = 1 - 2/(e^{2|x|}+1), restore sign
__device__ __forceinline__ float tanh_fast(float x) {
  float ax = fabsf(x);
  float e = __expf(2.0f * ax);
  float t = 1.0f - 2.0f * __builtin_amdgcn_rcpf(e + 1.0f);
  return copysignf(t, x);
}

__global__ void prep_weights(const float* __restrict__ Wix, const float* __restrict__ Wih,
                             const float* __restrict__ Wfx, const float* __restrict__ Wfh,
                             const float* __restrict__ Wox, const float* __restrict__ Woh,
                             const float* __restrict__ Wux, const float* __restrict__ Wuh,
                             u16* __restrict__ Wcat, u16* __restrict__ Wfxb, u16* __restrict__ Wfhb)
{
  int t = blockIdx.x * 256 + threadIdx.x;
  if (t < 98304) {                 // Wcat: 384 rows x 256 k
    int nrow = t >> 8, k = t & 255;
    int gate = nrow >> 7, r = nrow & 127;
    float v;
    if (k < 128) {
      const float* W = (gate == 0) ? Wix : (gate == 1) ? Wox : Wux;
      v = W[r * 128 + k];
    } else {
      const float* W = (gate == 0) ? Wih : (gate == 1) ? Woh : Wuh;
      v = W[r * 128 + (k - 128)];
    }
    Wcat[t] = f2bf(v);
  } else if (t < 98304 + 16384) {
    int i = t - 98304;
    Wfxb[i] = f2bf(Wfx[i]);
  } else if (t < 98304 + 32768) {
    int i = t - 98304 - 16384;
    Wfhb[i] = f2bf(Wfh[i]);
  }
}

// Per-level kernel. Block = 256 threads (4 waves), 32 parents (128 children).
// LEAF=1: no children (level 7): only i/o/u GEMM (K=128) + elementwise.
// LEAF=0: fx-GEMM -> LDS, h_sum -> LDS (swizzled bf16), fh-GEMM in acc,
//         f/fc in-lane reduce -> LDS, then K=256 GEMM [x|h_sum]@Wcat^T, epilogue.
template <int LEAF>
__global__ __launch_bounds__(256, 2)
void level_kernel(const float* __restrict__ embeds,
                  const u16* __restrict__ Wcat,
                  const u16* __restrict__ Wfxb,
                  const u16* __restrict__ Wfhb,
                  const float* __restrict__ bix, const float* __restrict__ bfx,
                  const float* __restrict__ box, const float* __restrict__ bux,
                  u16* __restrict__ h_all, float* __restrict__ c_all,
                  int n, int node_off, int child_off)
{
  extern __shared__ char smem[];
  u16*   s_hsum = (u16*)smem;                    // 32x128 bf16, XOR-swizzled (8 KB)
  float* s_fx   = (float*)(smem + 8192);         // 32x128 f32 (16 KB)
  float* s_fc   = (float*)(smem + 8192 + 16384); // 32x128 f32 (16 KB)

  const int tid  = threadIdx.x;
  const int wave = tid >> 6;
  const int lane = tid & 63;
  const int lg   = lane >> 4;   // lane group (k-offset group / acc row group)
  const int ln   = lane & 15;   // row (A) / col (B,C)
  const int pbase = blockIdx.x * 32;

  // ---- hoisted x A-fragments: rows = parent m*16+ln, k = kt*32+lg*8 ----
  short8 a_x[2][4];
  {
    const float* xb = embeds + (size_t)(node_off + pbase) * HID;
#pragma unroll
    for (int m = 0; m < 2; ++m)
#pragma unroll
      for (int kt = 0; kt < 4; ++kt) {
        const float* p = xb + (size_t)(m * 16 + ln) * HID + kt * 32 + lg * 8;
        float4 f0 = *(const float4*)p;
        float4 f1 = *(const float4*)(p + 4);
        short8 s;
        s[0] = (short)f2bf(f0.x); s[1] = (short)f2bf(f0.y);
        s[2] = (short)f2bf(f0.z); s[3] = (short)f2bf(f0.w);
        s[4] = (short)f2bf(f1.x); s[5] = (short)f2bf(f1.y);
        s[6] = (short)f2bf(f1.z); s[7] = (short)f2bf(f1.w);
        a_x[m][kt] = s;
      }
  }

  if constexpr (LEAF == 0) {
    // ---- fx GEMM: 32 parents x 128 cols; wave owns N-tiles {2w, 2w+1} ----
    floatx4 acc_fx[2][2] = {};
#pragma unroll
    for (int kt = 0; kt < 4; ++kt)
#pragma unroll
      for (int ntl = 0; ntl < 2; ++ntl) {
        int nt = wave * 2 + ntl;
        short8 b = *(const short8*)(Wfxb + (size_t)(nt * 16 + ln) * HID + kt * 32 + lg * 8);
#pragma unroll
        for (int m = 0; m < 2; ++m)
          acc_fx[m][ntl] = __builtin_amdgcn_mfma_f32_16x16x32_bf16(a_x[m][kt], b, acc_fx[m][ntl], 0, 0, 0);
      }
#pragma unroll
    for (int m = 0; m < 2; ++m)
#pragma unroll
      for (int ntl = 0; ntl < 2; ++ntl) {
        int col = (wave * 2 + ntl) * 16 + ln;
#pragma unroll
        for (int r = 0; r < 4; ++r) {
          int row = m * 16 + lg * 4 + r;
          s_fx[row * HID + col] = acc_fx[m][ntl][r];
        }
      }

    // ---- h_sum: thread -> parent p=tid>>3, 16 cols at (tid&7)*16 ----
    {
      int p = tid >> 3, cg = tid & 7;
      const u16* ch = h_all + (size_t)(child_off + 4 * (pbase + p)) * HID + cg * 16;
      float hs[16];
#pragma unroll
      for (int j = 0; j < 16; ++j) hs[j] = 0.f;
#pragma unroll
      for (int b = 0; b < 4; ++b) {
        short8 v0 = *(const short8*)(ch + (size_t)b * HID);
        short8 v1 = *(const short8*)(ch + (size_t)b * HID + 8);
#pragma unroll
        for (int j = 0; j < 8; ++j) {
          hs[j]     += bf2f((u16)v0[j]);
          hs[8 + j] += bf2f((u16)v1[j]);
        }
      }
      short8 o0, o1;
#pragma unroll
      for (int j = 0; j < 8; ++j) { o0[j] = (short)f2bf(hs[j]); o1[j] = (short)f2bf(hs[8 + j]); }
      unsigned sw = ((unsigned)(p & 7)) << 4;   // 16B XOR swizzle vs 256B row stride
      *(short8*)((char*)s_hsum + p * 256 + ((cg * 32) ^ sw))      = o0;
      *(short8*)((char*)s_hsum + p * 256 + ((cg * 32 + 16) ^ sw)) = o1;
    }

    // ---- fh GEMM: wave owns child rows [w*32, w*32+32), all 128 cols ----
    short8 a_h[2][4];
    {
      const u16* chb = h_all + (size_t)(child_off + 4 * pbase + wave * 32) * HID;
#pragma unroll
      for (int m = 0; m < 2; ++m)
#pragma unroll
        for (int kt = 0; kt < 4; ++kt)
          a_h[m][kt] = *(const short8*)(chb + (size_t)(m * 16 + ln) * HID + kt * 32 + lg * 8);
    }
    floatx4 acc_fh[2][8] = {};
#pragma unroll
    for (int kt = 0; kt < 4; ++kt)
#pragma unroll
      for (int nt = 0; nt < 8; ++nt) {
        short8 b = *(const short8*)(Wfhb + (size_t)(nt * 16 + ln) * HID + kt * 32 + lg * 8);
#pragma unroll
        for (int m = 0; m < 2; ++m)
          acc_fh[m][nt] = __builtin_amdgcn_mfma_f32_16x16x32_bf16(a_h[m][kt], b, acc_fh[m][nt], 0, 0, 0);
      }

    __syncthreads();

    // ---- f = sigm(fx + bfx + fh); fc_sum: 4 children live in this lane's 4 regs ----
#pragma unroll
    for (int m = 0; m < 2; ++m) {
      int ploc = wave * 8 + m * 4 + lg;
      const float* crow = c_all + (size_t)(child_off + 4 * pbase + wave * 32 + m * 16 + lg * 4) * HID;
#pragma unroll
      for (int nt = 0; nt < 8; ++nt) {
        int col = nt * 16 + ln;
        float fxv = s_fx[ploc * HID + col] + bfx[col];
        float fc = 0.f;
#pragma unroll
        for (int r = 0; r < 4; ++r) {
          float f = sigm(fxv + acc_fh[m][nt][r]);
          float cch = crow[(size_t)r * HID + col];
          fc += f * cch;
        }
        s_fc[ploc * HID + col] = fc;
      }
    }
    __syncthreads();
  }

  // ---- main GEMM: 32 parents x 384 (i|o|u), K=128 (leaf) / 256 (internal) ----
  // wave owns cols [w*32, w*32+32) WITHIN each gate -> epilogue is in-register.
  floatx4 acc[2][3][2] = {};
  constexpr int KT = LEAF ? 4 : 8;
#pragma unroll
  for (int kt = 0; kt < KT; ++kt) {
    short8 a[2];
    if (kt < 4) {
      a[0] = a_x[0][kt]; a[1] = a_x[1][kt];
    } else {
#pragma unroll
      for (int m = 0; m < 2; ++m) {
        int row = m * 16 + ln;
        unsigned sw = ((unsigned)(row & 7)) << 4;
        int kbyte = ((kt - 4) * 32 + lg * 8) * 2;
        a[m] = *(const short8*)((char*)s_hsum + row * 256 + (kbyte ^ sw));
      }
    }
#pragma unroll
    for (int g = 0; g < 3; ++g)
#pragma unroll
      for (int ntl = 0; ntl < 2; ++ntl) {
        int NT = g * 8 + wave * 2 + ntl;
        short8 b = *(const short8*)(Wcat + (size_t)(NT * 16 + ln) * 256 + kt * 32 + lg * 8);
#pragma unroll
        for (int m = 0; m < 2; ++m)
          acc[m][g][ntl] = __builtin_amdgcn_mfma_f32_16x16x32_bf16(a[m], b, acc[m][g][ntl], 0, 0, 0);
      }
  }

  // ---- epilogue: gates, c, h ----
#pragma unroll
  for (int m = 0; m < 2; ++m)
#pragma unroll
    for (int ntl = 0; ntl < 2; ++ntl) {
      int col = wave * 32 + ntl * 16 + ln;
      float bi = bix[col], bo = box[col], bu = bux[col];
#pragma unroll
      for (int r = 0; r < 4; ++r) {
        int row = m * 16 + lg * 4 + r;
        if (pbase + row < n) {
          float iv = sigm(acc[m][0][ntl][r] + bi);
          float ov = sigm(acc[m][1][ntl][r] + bo);
          float uv = tanh_fast(acc[m][2][ntl][r] + bu);
          float fc = (LEAF != 0) ? 0.f : s_fc[row * HID + col];
          float cv = iv * uv + fc;
          float hv = ov * tanh_fast(cv);
          size_t gidx = (size_t)(node_off + pbase + row) * HID + col;
          c_all[gidx] = cv;
          h_all[gidx] = f2bf(hv);
        }
      }
    }
}

__global__ void out_kernel(const u16* __restrict__ h_all, const float* __restrict__ Wout,
                           const float* __restrict__ bout, float* __restrict__ out)
{
  int t = threadIdx.x;
  if (t < 80) {                 // 16 roots x 5 labels
    int row = t / 5, lbl = t - row * 5;
    float s = bout[lbl];
    for (int k = 0; k < 128; ++k)
      s += bf2f(h_all[row * 128 + k]) * Wout[lbl * 128 + k];
    out[t] = s;
  }
}

extern "C" void kernel_launch(void* const* d_in, const int* in_sizes, int n_in,
                              void* d_out, int out_size, void* d_ws, size_t ws_size,
                              hipStream_t stream)
{
  const float* embeds = (const float*)d_in[0];
  const float* Wix = (const float*)d_in[1];
  const float* bix = (const float*)d_in[2];
  const float* Wih = (const float*)d_in[3];
  const float* Wfx = (const float*)d_in[4];
  const float* bfx = (const float*)d_in[5];
  const float* Wfh = (const float*)d_in[6];
  const float* Wox = (const float*)d_in[7];
  const float* box = (const float*)d_in[8];
  const float* Woh = (const float*)d_in[9];
  const float* Wux = (const float*)d_in[10];
  const float* bux = (const float*)d_in[11];
  const float* Wuh = (const float*)d_in[12];
  const float* Wout = (const float*)d_in[13];
  const float* bout = (const float*)d_in[14];

  static const int counts[8]  = {16, 64, 256, 1024, 4096, 16384, 65536, 262144};
  static const int offsets[9] = {0, 16, 80, 336, 1360, 5456, 21840, 87376, 349520};

  char* ws = (char*)d_ws;
  u16*   h_all = (u16*)ws;                                   // 89,477,120 B
  float* c_all = (float*)(ws + 89477120);                    // 178,954,240 B
  u16*   Wcat  = (u16*)(ws + 89477120 + 178954240);          // 384*256*2
  u16*   Wfxb  = Wcat + 384 * 256;
  u16*   Wfhb  = Wfxb + 128 * 128;

  prep_weights<<<512, 256, 0, stream>>>(Wix, Wih, Wfx, Wfh, Wox, Woh, Wux, Wuh,
                                        Wcat, Wfxb, Wfhb);

  // level 7 (leaves)
  level_kernel<1><<<262144 / 32, 256, 0, stream>>>(
      embeds, Wcat, Wfxb, Wfhb, bix, bfx, box, bux,
      h_all, c_all, 262144, 87376, 0);

  // levels 6..0 (internal)
  for (int l = 6; l >= 0; --l) {
    int n = counts[l];
    int grid = (n + 31) / 32;
    level_kernel<0><<<grid, 256, 40960, stream>>>(
        embeds, Wcat, Wfxb, Wfhb, bix, bfx, box, bux,
        h_all, c_all, n, offsets[l], offsets[l + 1]);
  }

  out_kernel<<<1, 128, 0, stream>>>(h_all, Wout, bout, (float*)d_out);
}

// Round 7
// 383.090 us; speedup vs baseline: 1.2710x; 1.2079x over previous
//
#include <hip/hip_runtime.h>

// Child-Sum Tree-LSTM, 16 trees x branch4 x depth8, HIDDEN=IN_DIM=128.
// R6: leaf restructured as tiled GEMM: M=128/block, x staged in swizzled LDS,
//     2 M-halves of 96-reg acc, 192 MFMA/wave. Internal levels unchanged (R5).

#define HID 128

typedef unsigned short u16;
typedef __attribute__((ext_vector_type(8))) short short8;
typedef __attribute__((ext_vector_type(4))) float floatx4;

__device__ __forceinline__ float bf2f(u16 u) {
  union { unsigned int u; float f; } v; v.u = ((unsigned int)u) << 16; return v.f;
}
__device__ __forceinline__ u16 f2bf(float f) {
  union { float f; unsigned int u; } v; v.f = f;
  unsigned int r = v.u + 0x7FFFu + ((v.u >> 16) & 1u);
  return (u16)(r >> 16);
}
__device__ __forceinline__ short8 f2bf8(float4 f0, float4 f1) {
  short8 s;
  s[0] = (short)f2bf(f0.x); s[1] = (short)f2bf(f0.y);
  s[2] = (short)f2bf(f0.z); s[3] = (short)f2bf(f0.w);
  s[4] = (short)f2bf(f1.x); s[5] = (short)f2bf(f1.y);
  s[6] = (short)f2bf(f1.z); s[7] = (short)f2bf(f1.w);
  return s;
}
// sigm(x) = 1/(1+e^-x) via v_rcp_f32 (no IEEE div sequence)
__device__ __forceinline__ float sigm(float x) {
  return __builtin_amdgcn_rcpf(1.0f + __expf(-x));
}
// tanh(|x|) = 1 - 2/(e^{2|x|}+1), restore sign
__device__ __forceinline__ float tanh_fast(float x) {
  float ax = fabsf(x);
  float e = __expf(2.0f * ax);
  float t = 1.0f - 2.0f * __builtin_amdgcn_rcpf(e + 1.0f);
  return copysignf(t, x);
}

__global__ void prep_weights(const float* __restrict__ Wix, const float* __restrict__ Wih,
                             const float* __restrict__ Wfx, const float* __restrict__ Wfh,
                             const float* __restrict__ Wox, const float* __restrict__ Woh,
                             const float* __restrict__ Wux, const float* __restrict__ Wuh,
                             u16* __restrict__ Wcat, u16* __restrict__ Wfxb, u16* __restrict__ Wfhb)
{
  int t = blockIdx.x * 256 + threadIdx.x;
  if (t < 98304) {                 // Wcat: 384 rows x 256 k
    int nrow = t >> 8, k = t & 255;
    int gate = nrow >> 7, r = nrow & 127;
    float v;
    if (k < 128) {
      const float* W = (gate == 0) ? Wix : (gate == 1) ? Wox : Wux;
      v = W[r * 128 + k];
    } else {
      const float* W = (gate == 0) ? Wih : (gate == 1) ? Woh : Wuh;
      v = W[r * 128 + (k - 128)];
    }
    Wcat[t] = f2bf(v);
  } else if (t < 98304 + 16384) {
    int i = t - 98304;
    Wfxb[i] = f2bf(Wfx[i]);
  } else if (t < 98304 + 32768) {
    int i = t - 98304 - 16384;
    Wfhb[i] = f2bf(Wfh[i]);
  }
}

// ---------------- Leaf kernel: tiled GEMM, M=128 per block ----------------
// Block = 256 threads (4 waves). x-tile (128x128) staged once as swizzled bf16
// in LDS. Wave w owns within-gate cols [w*32,(w+1)*32) for gates i,o,u.
// Two M-halves (64 rows each) keep acc at 96 f32/lane.
__global__ __launch_bounds__(256, 2)
void leaf_kernel(const float* __restrict__ embeds,
                 const u16* __restrict__ Wcat,
                 const float* __restrict__ bix, const float* __restrict__ box,
                 const float* __restrict__ bux,
                 u16* __restrict__ h_all, float* __restrict__ c_all,
                 int node_off)
{
  __shared__ char smem[32768];           // 128 rows x 256 B (bf16), XOR-swizzled
  u16* sx = (u16*)smem;

  const int tid  = threadIdx.x;
  const int wave = tid >> 6;
  const int lane = tid & 63;
  const int lg   = lane >> 4;
  const int ln   = lane & 15;
  const int pbase = blockIdx.x * 128;

  // ---- stage x: thread t -> row t>>1, 64-float half (t&1) ----
  {
    int row = tid >> 1;
    int k0  = (tid & 1) * 64;
    const float* src = embeds + (size_t)(node_off + pbase + row) * HID + k0;
    unsigned sw = ((unsigned)(row & 7)) << 4;
    char* dst = (char*)sx + row * 256;
#pragma unroll
    for (int j = 0; j < 8; ++j) {
      float4 f0 = *(const float4*)(src + j * 8);
      float4 f1 = *(const float4*)(src + j * 8 + 4);
      *(short8*)(dst + (((unsigned)((k0 + j * 8) * 2)) ^ sw)) = f2bf8(f0, f1);
    }
  }

  float bi[2], bo[2], bu[2];
#pragma unroll
  for (int ntl = 0; ntl < 2; ++ntl) {
    int col = wave * 32 + ntl * 16 + ln;
    bi[ntl] = bix[col]; bo[ntl] = box[col]; bu[ntl] = bux[col];
  }

  __syncthreads();

  // ---- two M-halves: GEMM (K=128) + fused epilogue ----
#pragma unroll
  for (int hm = 0; hm < 2; ++hm) {
    floatx4 acc[4][3][2] = {};
#pragma unroll
    for (int kt = 0; kt < 4; ++kt) {
      short8 a[4];
#pragma unroll
      for (int m = 0; m < 4; ++m) {
        int row = hm * 64 + m * 16 + ln;
        unsigned sw = ((unsigned)(row & 7)) << 4;
        a[m] = *(const short8*)((char*)sx + row * 256 +
                                (((unsigned)((kt * 32 + lg * 8) * 2)) ^ sw));
      }
#pragma unroll
      for (int g = 0; g < 3; ++g)
#pragma unroll
        for (int ntl = 0; ntl < 2; ++ntl) {
          int NT = g * 8 + wave * 2 + ntl;
          short8 b = *(const short8*)(Wcat + (size_t)(NT * 16 + ln) * 256 + kt * 32 + lg * 8);
#pragma unroll
          for (int m = 0; m < 4; ++m)
            acc[m][g][ntl] = __builtin_amdgcn_mfma_f32_16x16x32_bf16(a[m], b, acc[m][g][ntl], 0, 0, 0);
        }
    }
#pragma unroll
    for (int m = 0; m < 4; ++m)
#pragma unroll
      for (int ntl = 0; ntl < 2; ++ntl) {
        int col = wave * 32 + ntl * 16 + ln;
#pragma unroll
        for (int r = 0; r < 4; ++r) {
          int row = hm * 64 + m * 16 + lg * 4 + r;
          float iv = sigm(acc[m][0][ntl][r] + bi[ntl]);
          float ov = sigm(acc[m][1][ntl][r] + bo[ntl]);
          float uv = tanh_fast(acc[m][2][ntl][r] + bu[ntl]);
          float cv = iv * uv;
          float hv = ov * tanh_fast(cv);
          size_t gidx = (size_t)(node_off + pbase + row) * HID + col;
          c_all[gidx] = cv;
          h_all[gidx] = f2bf(hv);
        }
      }
  }
}

// ---------------- Internal-level kernel (unchanged from R5) ----------------
__global__ __launch_bounds__(256, 2)
void level_kernel(const float* __restrict__ embeds,
                  const u16* __restrict__ Wcat,
                  const u16* __restrict__ Wfxb,
                  const u16* __restrict__ Wfhb,
                  const float* __restrict__ bix, const float* __restrict__ bfx,
                  const float* __restrict__ box, const float* __restrict__ bux,
                  u16* __restrict__ h_all, float* __restrict__ c_all,
                  int n, int node_off, int child_off)
{
  extern __shared__ char smem[];
  u16*   s_hsum = (u16*)smem;                    // 32x128 bf16, XOR-swizzled (8 KB)
  float* s_fx   = (float*)(smem + 8192);         // 32x128 f32 (16 KB)
  float* s_fc   = (float*)(smem + 8192 + 16384); // 32x128 f32 (16 KB)

  const int tid  = threadIdx.x;
  const int wave = tid >> 6;
  const int lane = tid & 63;
  const int lg   = lane >> 4;
  const int ln   = lane & 15;
  const int pbase = blockIdx.x * 32;

  short8 a_x[2][4];
  {
    const float* xb = embeds + (size_t)(node_off + pbase) * HID;
#pragma unroll
    for (int m = 0; m < 2; ++m)
#pragma unroll
      for (int kt = 0; kt < 4; ++kt) {
        const float* p = xb + (size_t)(m * 16 + ln) * HID + kt * 32 + lg * 8;
        float4 f0 = *(const float4*)p;
        float4 f1 = *(const float4*)(p + 4);
        a_x[m][kt] = f2bf8(f0, f1);
      }
  }

  // ---- fx GEMM ----
  floatx4 acc_fx[2][2] = {};
#pragma unroll
  for (int kt = 0; kt < 4; ++kt)
#pragma unroll
    for (int ntl = 0; ntl < 2; ++ntl) {
      int nt = wave * 2 + ntl;
      short8 b = *(const short8*)(Wfxb + (size_t)(nt * 16 + ln) * HID + kt * 32 + lg * 8);
#pragma unroll
      for (int m = 0; m < 2; ++m)
        acc_fx[m][ntl] = __builtin_amdgcn_mfma_f32_16x16x32_bf16(a_x[m][kt], b, acc_fx[m][ntl], 0, 0, 0);
    }
#pragma unroll
  for (int m = 0; m < 2; ++m)
#pragma unroll
    for (int ntl = 0; ntl < 2; ++ntl) {
      int col = (wave * 2 + ntl) * 16 + ln;
#pragma unroll
      for (int r = 0; r < 4; ++r) {
        int row = m * 16 + lg * 4 + r;
        s_fx[row * HID + col] = acc_fx[m][ntl][r];
      }
    }

  // ---- h_sum ----
  {
    int p = tid >> 3, cg = tid & 7;
    const u16* ch = h_all + (size_t)(child_off + 4 * (pbase + p)) * HID + cg * 16;
    float hs[16];
#pragma unroll
    for (int j = 0; j < 16; ++j) hs[j] = 0.f;
#pragma unroll
    for (int b = 0; b < 4; ++b) {
      short8 v0 = *(const short8*)(ch + (size_t)b * HID);
      short8 v1 = *(const short8*)(ch + (size_t)b * HID + 8);
#pragma unroll
      for (int j = 0; j < 8; ++j) {
        hs[j]     += bf2f((u16)v0[j]);
        hs[8 + j] += bf2f((u16)v1[j]);
      }
    }
    short8 o0, o1;
#pragma unroll
    for (int j = 0; j < 8; ++j) { o0[j] = (short)f2bf(hs[j]); o1[j] = (short)f2bf(hs[8 + j]); }
    unsigned sw = ((unsigned)(p & 7)) << 4;
    *(short8*)((char*)s_hsum + p * 256 + ((cg * 32) ^ sw))      = o0;
    *(short8*)((char*)s_hsum + p * 256 + ((cg * 32 + 16) ^ sw)) = o1;
  }

  // ---- fh GEMM ----
  short8 a_h[2][4];
  {
    const u16* chb = h_all + (size_t)(child_off + 4 * pbase + wave * 32) * HID;
#pragma unroll
    for (int m = 0; m < 2; ++m)
#pragma unroll
      for (int kt = 0; kt < 4; ++kt)
        a_h[m][kt] = *(const short8*)(chb + (size_t)(m * 16 + ln) * HID + kt * 32 + lg * 8);
  }
  floatx4 acc_fh[2][8] = {};
#pragma unroll
  for (int kt = 0; kt < 4; ++kt)
#pragma unroll
    for (int nt = 0; nt < 8; ++nt) {
      short8 b = *(const short8*)(Wfhb + (size_t)(nt * 16 + ln) * HID + kt * 32 + lg * 8);
#pragma unroll
      for (int m = 0; m < 2; ++m)
        acc_fh[m][nt] = __builtin_amdgcn_mfma_f32_16x16x32_bf16(a_h[m][kt], b, acc_fh[m][nt], 0, 0, 0);
    }

  __syncthreads();

  // ---- f, fc_sum ----
#pragma unroll
  for (int m = 0; m < 2; ++m) {
    int ploc = wave * 8 + m * 4 + lg;
    const float* crow = c_all + (size_t)(child_off + 4 * pbase + wave * 32 + m * 16 + lg * 4) * HID;
#pragma unroll
    for (int nt = 0; nt < 8; ++nt) {
      int col = nt * 16 + ln;
      float fxv = s_fx[ploc * HID + col] + bfx[col];
      float fc = 0.f;
#pragma unroll
      for (int r = 0; r < 4; ++r) {
        float f = sigm(fxv + acc_fh[m][nt][r]);
        float cch = crow[(size_t)r * HID + col];
        fc += f * cch;
      }
      s_fc[ploc * HID + col] = fc;
    }
  }
  __syncthreads();

  // ---- main GEMM: K=256 ----
  floatx4 acc[2][3][2] = {};
#pragma unroll
  for (int kt = 0; kt < 8; ++kt) {
    short8 a[2];
    if (kt < 4) {
      a[0] = a_x[0][kt]; a[1] = a_x[1][kt];
    } else {
#pragma unroll
      for (int m = 0; m < 2; ++m) {
        int row = m * 16 + ln;
        unsigned sw = ((unsigned)(row & 7)) << 4;
        int kbyte = ((kt - 4) * 32 + lg * 8) * 2;
        a[m] = *(const short8*)((char*)s_hsum + row * 256 + (kbyte ^ sw));
      }
    }
#pragma unroll
    for (int g = 0; g < 3; ++g)
#pragma unroll
      for (int ntl = 0; ntl < 2; ++ntl) {
        int NT = g * 8 + wave * 2 + ntl;
        short8 b = *(const short8*)(Wcat + (size_t)(NT * 16 + ln) * 256 + kt * 32 + lg * 8);
#pragma unroll
        for (int m = 0; m < 2; ++m)
          acc[m][g][ntl] = __builtin_amdgcn_mfma_f32_16x16x32_bf16(a[m], b, acc[m][g][ntl], 0, 0, 0);
      }
  }

  // ---- epilogue ----
#pragma unroll
  for (int m = 0; m < 2; ++m)
#pragma unroll
    for (int ntl = 0; ntl < 2; ++ntl) {
      int col = wave * 32 + ntl * 16 + ln;
      float bi = bix[col], bo = box[col], bu = bux[col];
#pragma unroll
      for (int r = 0; r < 4; ++r) {
        int row = m * 16 + lg * 4 + r;
        if (pbase + row < n) {
          float iv = sigm(acc[m][0][ntl][r] + bi);
          float ov = sigm(acc[m][1][ntl][r] + bo);
          float uv = tanh_fast(acc[m][2][ntl][r] + bu);
          float fc = s_fc[row * HID + col];
          float cv = iv * uv + fc;
          float hv = ov * tanh_fast(cv);
          size_t gidx = (size_t)(node_off + pbase + row) * HID + col;
          c_all[gidx] = cv;
          h_all[gidx] = f2bf(hv);
        }
      }
    }
}

__global__ void out_kernel(const u16* __restrict__ h_all, const float* __restrict__ Wout,
                           const float* __restrict__ bout, float* __restrict__ out)
{
  int t = threadIdx.x;
  if (t < 80) {                 // 16 roots x 5 labels
    int row = t / 5, lbl = t - row * 5;
    float s = bout[lbl];
    for (int k = 0; k < 128; ++k)
      s += bf2f(h_all[row * 128 + k]) * Wout[lbl * 128 + k];
    out[t] = s;
  }
}

extern "C" void kernel_launch(void* const* d_in, const int* in_sizes, int n_in,
                              void* d_out, int out_size, void* d_ws, size_t ws_size,
                              hipStream_t stream)
{
  const float* embeds = (const float*)d_in[0];
  const float* Wix = (const float*)d_in[1];
  const float* bix = (const float*)d_in[2];
  const float* Wih = (const float*)d_in[3];
  const float* Wfx = (const float*)d_in[4];
  const float* bfx = (const float*)d_in[5];
  const float* Wfh = (const float*)d_in[6];
  const float* Wox = (const float*)d_in[7];
  const float* box = (const float*)d_in[8];
  const float* Woh = (const float*)d_in[9];
  const float* Wux = (const float*)d_in[10];
  const float* bux = (const float*)d_in[11];
  const float* Wuh = (const float*)d_in[12];
  const float* Wout = (const float*)d_in[13];
  const float* bout = (const float*)d_in[14];

  static const int counts[8]  = {16, 64, 256, 1024, 4096, 16384, 65536, 262144};
  static const int offsets[9] = {0, 16, 80, 336, 1360, 5456, 21840, 87376, 349520};

  char* ws = (char*)d_ws;
  u16*   h_all = (u16*)ws;                                   // 89,477,120 B
  float* c_all = (float*)(ws + 89477120);                    // 178,954,240 B
  u16*   Wcat  = (u16*)(ws + 89477120 + 178954240);          // 384*256*2
  u16*   Wfxb  = Wcat + 384 * 256;
  u16*   Wfhb  = Wfxb + 128 * 128;

  prep_weights<<<512, 256, 0, stream>>>(Wix, Wih, Wfx, Wfh, Wox, Woh, Wux, Wuh,
                                        Wcat, Wfxb, Wfhb);

  // level 7 (leaves): tiled GEMM, 128 nodes/block
  leaf_kernel<<<262144 / 128, 256, 0, stream>>>(
      embeds, Wcat, bix, box, bux, h_all, c_all, 87376);

  // levels 6..0 (internal)
  for (int l = 6; l >= 0; --l) {
    int n = counts[l];
    int grid = (n + 31) / 32;
    level_kernel<<<grid, 256, 40960, stream>>>(
        embeds, Wcat, Wfxb, Wfhb, bix, bfx, box, bux,
        h_all, c_all, n, offsets[l], offsets[l + 1]);
  }

  out_kernel<<<1, 128, 0, stream>>>(h_all, Wout, bout, (float*)d_out);
}

// Round 8
// 368.270 us; speedup vs baseline: 1.3221x; 1.0402x over previous
//
#include <hip/hip_runtime.h>

// Child-Sum Tree-LSTM, 16 trees x branch4 x depth8, HIDDEN=IN_DIM=128.
// R8: leaf = M=64/block, 512 threads (8 waves), wave owns 16 cols per gate
//     -> acc 48 f32/lane (was 96), occupancy 2->4+ waves/SIMD. Internals = R5.

#define HID 128

typedef unsigned short u16;
typedef __attribute__((ext_vector_type(8))) short short8;
typedef __attribute__((ext_vector_type(4))) float floatx4;

__device__ __forceinline__ float bf2f(u16 u) {
  union { unsigned int u; float f; } v; v.u = ((unsigned int)u) << 16; return v.f;
}
__device__ __forceinline__ u16 f2bf(float f) {
  union { float f; unsigned int u; } v; v.f = f;
  unsigned int r = v.u + 0x7FFFu + ((v.u >> 16) & 1u);
  return (u16)(r >> 16);
}
__device__ __forceinline__ short8 f2bf8(float4 f0, float4 f1) {
  short8 s;
  s[0] = (short)f2bf(f0.x); s[1] = (short)f2bf(f0.y);
  s[2] = (short)f2bf(f0.z); s[3] = (short)f2bf(f0.w);
  s[4] = (short)f2bf(f1.x); s[5] = (short)f2bf(f1.y);
  s[6] = (short)f2bf(f1.z); s[7] = (short)f2bf(f1.w);
  return s;
}
// sigm(x) = 1/(1+e^-x) via v_rcp_f32 (no IEEE div sequence)
__device__ __forceinline__ float sigm(float x) {
  return __builtin_amdgcn_rcpf(1.0f + __expf(-x));
}
// tanh(|x|) = 1 - 2/(e^{2|x|}+1), restore sign
__device__ __forceinline__ float tanh_fast(float x) {
  float ax = fabsf(x);
  float e = __expf(2.0f * ax);
  float t = 1.0f - 2.0f * __builtin_amdgcn_rcpf(e + 1.0f);
  return copysignf(t, x);
}

__global__ void prep_weights(const float* __restrict__ Wix, const float* __restrict__ Wih,
                             const float* __restrict__ Wfx, const float* __restrict__ Wfh,
                             const float* __restrict__ Wox, const float* __restrict__ Woh,
                             const float* __restrict__ Wux, const float* __restrict__ Wuh,
                             u16* __restrict__ Wcat, u16* __restrict__ Wfxb, u16* __restrict__ Wfhb)
{
  int t = blockIdx.x * 256 + threadIdx.x;
  if (t < 98304) {                 // Wcat: 384 rows x 256 k
    int nrow = t >> 8, k = t & 255;
    int gate = nrow >> 7, r = nrow & 127;
    float v;
    if (k < 128) {
      const float* W = (gate == 0) ? Wix : (gate == 1) ? Wox : Wux;
      v = W[r * 128 + k];
    } else {
      const float* W = (gate == 0) ? Wih : (gate == 1) ? Woh : Wuh;
      v = W[r * 128 + (k - 128)];
    }
    Wcat[t] = f2bf(v);
  } else if (t < 98304 + 16384) {
    int i = t - 98304;
    Wfxb[i] = f2bf(Wfx[i]);
  } else if (t < 98304 + 32768) {
    int i = t - 98304 - 16384;
    Wfhb[i] = f2bf(Wfh[i]);
  }
}

// ---------------- Leaf kernel: M=64/block, 8 waves, 48-reg acc ----------------
// Wave w owns cols [w*16,(w+1)*16) WITHIN each of the 3 gates (i,o,u) ->
// epilogue fully in-register. x-tile (64x128) staged swizzled bf16 in LDS.
__global__ __launch_bounds__(512, 2)
void leaf_kernel(const float* __restrict__ embeds,
                 const u16* __restrict__ Wcat,
                 const float* __restrict__ bix, const float* __restrict__ box,
                 const float* __restrict__ bux,
                 u16* __restrict__ h_all, float* __restrict__ c_all,
                 int node_off)
{
  __shared__ char smem[16384];           // 64 rows x 256 B (bf16), XOR-swizzled
  u16* sx = (u16*)smem;

  const int tid  = threadIdx.x;
  const int wave = tid >> 6;             // 0..7
  const int lane = tid & 63;
  const int lg   = lane >> 4;
  const int ln   = lane & 15;
  const int pbase = blockIdx.x * 64;

  // ---- stage x: thread t -> row t>>3, 16-float chunk (t&7) ----
  {
    int row = tid >> 3;
    int k0  = (tid & 7) * 16;            // float index
    const float* src = embeds + (size_t)(node_off + pbase + row) * HID + k0;
    unsigned sw = ((unsigned)(row & 7)) << 4;
    char* dst = (char*)sx + row * 256;
    float4 f0 = *(const float4*)src;
    float4 f1 = *(const float4*)(src + 4);
    float4 f2 = *(const float4*)(src + 8);
    float4 f3 = *(const float4*)(src + 12);
    *(short8*)(dst + (((unsigned)(k0 * 2)) ^ sw))      = f2bf8(f0, f1);
    *(short8*)(dst + (((unsigned)(k0 * 2 + 16)) ^ sw)) = f2bf8(f2, f3);
  }

  const int col = wave * 16 + ln;        // within-gate column
  const float bi = bix[col], bo = box[col], bu = bux[col];

  __syncthreads();

  // ---- GEMM: 64 rows x {i,o,u} x 16 cols, K=128 ----
  floatx4 acc[4][3] = {};
#pragma unroll
  for (int kt = 0; kt < 4; ++kt) {
    short8 a[4];
#pragma unroll
    for (int m = 0; m < 4; ++m) {
      int row = m * 16 + ln;
      unsigned sw = ((unsigned)(row & 7)) << 4;
      a[m] = *(const short8*)((char*)sx + row * 256 +
                              (((unsigned)((kt * 32 + lg * 8) * 2)) ^ sw));
    }
#pragma unroll
    for (int g = 0; g < 3; ++g) {
      int NT = g * 8 + wave;
      short8 b = *(const short8*)(Wcat + (size_t)(NT * 16 + ln) * 256 + kt * 32 + lg * 8);
#pragma unroll
      for (int m = 0; m < 4; ++m)
        acc[m][g] = __builtin_amdgcn_mfma_f32_16x16x32_bf16(a[m], b, acc[m][g], 0, 0, 0);
    }
  }

  // ---- epilogue: gates, c, h (all in-register) ----
#pragma unroll
  for (int m = 0; m < 4; ++m)
#pragma unroll
    for (int r = 0; r < 4; ++r) {
      int row = m * 16 + lg * 4 + r;
      float iv = sigm(acc[m][0][r] + bi);
      float ov = sigm(acc[m][1][r] + bo);
      float uv = tanh_fast(acc[m][2][r] + bu);
      float cv = iv * uv;
      float hv = ov * tanh_fast(cv);
      size_t gidx = (size_t)(node_off + pbase + row) * HID + col;
      c_all[gidx] = cv;
      h_all[gidx] = f2bf(hv);
    }
}

// ---------------- Internal-level kernel (unchanged from R5/R7) ----------------
__global__ __launch_bounds__(256, 2)
void level_kernel(const float* __restrict__ embeds,
                  const u16* __restrict__ Wcat,
                  const u16* __restrict__ Wfxb,
                  const u16* __restrict__ Wfhb,
                  const float* __restrict__ bix, const float* __restrict__ bfx,
                  const float* __restrict__ box, const float* __restrict__ bux,
                  u16* __restrict__ h_all, float* __restrict__ c_all,
                  int n, int node_off, int child_off)
{
  extern __shared__ char smem[];
  u16*   s_hsum = (u16*)smem;                    // 32x128 bf16, XOR-swizzled (8 KB)
  float* s_fx   = (float*)(smem + 8192);         // 32x128 f32 (16 KB)
  float* s_fc   = (float*)(smem + 8192 + 16384); // 32x128 f32 (16 KB)

  const int tid  = threadIdx.x;
  const int wave = tid >> 6;
  const int lane = tid & 63;
  const int lg   = lane >> 4;
  const int ln   = lane & 15;
  const int pbase = blockIdx.x * 32;

  short8 a_x[2][4];
  {
    const float* xb = embeds + (size_t)(node_off + pbase) * HID;
#pragma unroll
    for (int m = 0; m < 2; ++m)
#pragma unroll
      for (int kt = 0; kt < 4; ++kt) {
        const float* p = xb + (size_t)(m * 16 + ln) * HID + kt * 32 + lg * 8;
        float4 f0 = *(const float4*)p;
        float4 f1 = *(const float4*)(p + 4);
        a_x[m][kt] = f2bf8(f0, f1);
      }
  }

  // ---- fx GEMM ----
  floatx4 acc_fx[2][2] = {};
#pragma unroll
  for (int kt = 0; kt < 4; ++kt)
#pragma unroll
    for (int ntl = 0; ntl < 2; ++ntl) {
      int nt = wave * 2 + ntl;
      short8 b = *(const short8*)(Wfxb + (size_t)(nt * 16 + ln) * HID + kt * 32 + lg * 8);
#pragma unroll
      for (int m = 0; m < 2; ++m)
        acc_fx[m][ntl] = __builtin_amdgcn_mfma_f32_16x16x32_bf16(a_x[m][kt], b, acc_fx[m][ntl], 0, 0, 0);
    }
#pragma unroll
  for (int m = 0; m < 2; ++m)
#pragma unroll
    for (int ntl = 0; ntl < 2; ++ntl) {
      int col = (wave * 2 + ntl) * 16 + ln;
#pragma unroll
      for (int r = 0; r < 4; ++r) {
        int row = m * 16 + lg * 4 + r;
        s_fx[row * HID + col] = acc_fx[m][ntl][r];
      }
    }

  // ---- h_sum ----
  {
    int p = tid >> 3, cg = tid & 7;
    const u16* ch = h_all + (size_t)(child_off + 4 * (pbase + p)) * HID + cg * 16;
    float hs[16];
#pragma unroll
    for (int j = 0; j < 16; ++j) hs[j] = 0.f;
#pragma unroll
    for (int b = 0; b < 4; ++b) {
      short8 v0 = *(const short8*)(ch + (size_t)b * HID);
      short8 v1 = *(const short8*)(ch + (size_t)b * HID + 8);
#pragma unroll
      for (int j = 0; j < 8; ++j) {
        hs[j]     += bf2f((u16)v0[j]);
        hs[8 + j] += bf2f((u16)v1[j]);
      }
    }
    short8 o0, o1;
#pragma unroll
    for (int j = 0; j < 8; ++j) { o0[j] = (short)f2bf(hs[j]); o1[j] = (short)f2bf(hs[8 + j]); }
    unsigned sw = ((unsigned)(p & 7)) << 4;
    *(short8*)((char*)s_hsum + p * 256 + ((cg * 32) ^ sw))      = o0;
    *(short8*)((char*)s_hsum + p * 256 + ((cg * 32 + 16) ^ sw)) = o1;
  }

  // ---- fh GEMM ----
  short8 a_h[2][4];
  {
    const u16* chb = h_all + (size_t)(child_off + 4 * pbase + wave * 32) * HID;
#pragma unroll
    for (int m = 0; m < 2; ++m)
#pragma unroll
      for (int kt = 0; kt < 4; ++kt)
        a_h[m][kt] = *(const short8*)(chb + (size_t)(m * 16 + ln) * HID + kt * 32 + lg * 8);
  }
  floatx4 acc_fh[2][8] = {};
#pragma unroll
  for (int kt = 0; kt < 4; ++kt)
#pragma unroll
    for (int nt = 0; nt < 8; ++nt) {
      short8 b = *(const short8*)(Wfhb + (size_t)(nt * 16 + ln) * HID + kt * 32 + lg * 8);
#pragma unroll
      for (int m = 0; m < 2; ++m)
        acc_fh[m][nt] = __builtin_amdgcn_mfma_f32_16x16x32_bf16(a_h[m][kt], b, acc_fh[m][nt], 0, 0, 0);
    }

  __syncthreads();

  // ---- f, fc_sum ----
#pragma unroll
  for (int m = 0; m < 2; ++m) {
    int ploc = wave * 8 + m * 4 + lg;
    const float* crow = c_all + (size_t)(child_off + 4 * pbase + wave * 32 + m * 16 + lg * 4) * HID;
#pragma unroll
    for (int nt = 0; nt < 8; ++nt) {
      int col = nt * 16 + ln;
      float fxv = s_fx[ploc * HID + col] + bfx[col];
      float fc = 0.f;
#pragma unroll
      for (int r = 0; r < 4; ++r) {
        float f = sigm(fxv + acc_fh[m][nt][r]);
        float cch = crow[(size_t)r * HID + col];
        fc += f * cch;
      }
      s_fc[ploc * HID + col] = fc;
    }
  }
  __syncthreads();

  // ---- main GEMM: K=256 ----
  floatx4 acc[2][3][2] = {};
#pragma unroll
  for (int kt = 0; kt < 8; ++kt) {
    short8 a[2];
    if (kt < 4) {
      a[0] = a_x[0][kt]; a[1] = a_x[1][kt];
    } else {
#pragma unroll
      for (int m = 0; m < 2; ++m) {
        int row = m * 16 + ln;
        unsigned sw = ((unsigned)(row & 7)) << 4;
        int kbyte = ((kt - 4) * 32 + lg * 8) * 2;
        a[m] = *(const short8*)((char*)s_hsum + row * 256 + (kbyte ^ sw));
      }
    }
#pragma unroll
    for (int g = 0; g < 3; ++g)
#pragma unroll
      for (int ntl = 0; ntl < 2; ++ntl) {
        int NT = g * 8 + wave * 2 + ntl;
        short8 b = *(const short8*)(Wcat + (size_t)(NT * 16 + ln) * 256 + kt * 32 + lg * 8);
#pragma unroll
        for (int m = 0; m < 2; ++m)
          acc[m][g][ntl] = __builtin_amdgcn_mfma_f32_16x16x32_bf16(a[m], b, acc[m][g][ntl], 0, 0, 0);
      }
  }

  // ---- epilogue ----
#pragma unroll
  for (int m = 0; m < 2; ++m)
#pragma unroll
    for (int ntl = 0; ntl < 2; ++ntl) {
      int col = wave * 32 + ntl * 16 + ln;
      float bi = bix[col], bo = box[col], bu = bux[col];
#pragma unroll
      for (int r = 0; r < 4; ++r) {
        int row = m * 16 + lg * 4 + r;
        if (pbase + row < n) {
          float iv = sigm(acc[m][0][ntl][r] + bi);
          float ov = sigm(acc[m][1][ntl][r] + bo);
          float uv = tanh_fast(acc[m][2][ntl][r] + bu);
          float fc = s_fc[row * HID + col];
          float cv = iv * uv + fc;
          float hv = ov * tanh_fast(cv);
          size_t gidx = (size_t)(node_off + pbase + row) * HID + col;
          c_all[gidx] = cv;
          h_all[gidx] = f2bf(hv);
        }
      }
    }
}

__global__ void out_kernel(const u16* __restrict__ h_all, const float* __restrict__ Wout,
                           const float* __restrict__ bout, float* __restrict__ out)
{
  int t = threadIdx.x;
  if (t < 80) {                 // 16 roots x 5 labels
    int row = t / 5, lbl = t - row * 5;
    float s = bout[lbl];
    for (int k = 0; k < 128; ++k)
      s += bf2f(h_all[row * 128 + k]) * Wout[lbl * 128 + k];
    out[t] = s;
  }
}

extern "C" void kernel_launch(void* const* d_in, const int* in_sizes, int n_in,
                              void* d_out, int out_size, void* d_ws, size_t ws_size,
                              hipStream_t stream)
{
  const float* embeds = (const float*)d_in[0];
  const float* Wix = (const float*)d_in[1];
  const float* bix = (const float*)d_in[2];
  const float* Wih = (const float*)d_in[3];
  const float* Wfx = (const float*)d_in[4];
  const float* bfx = (const float*)d_in[5];
  const float* Wfh = (const float*)d_in[6];
  const float* Wox = (const float*)d_in[7];
  const float* box = (const float*)d_in[8];
  const float* Woh = (const float*)d_in[9];
  const float* Wux = (const float*)d_in[10];
  const float* bux = (const float*)d_in[11];
  const float* Wuh = (const float*)d_in[12];
  const float* Wout = (const float*)d_in[13];
  const float* bout = (const float*)d_in[14];

  static const int counts[8]  = {16, 64, 256, 1024, 4096, 16384, 65536, 262144};
  static const int offsets[9] = {0, 16, 80, 336, 1360, 5456, 21840, 87376, 349520};

  char* ws = (char*)d_ws;
  u16*   h_all = (u16*)ws;                                   // 89,477,120 B
  float* c_all = (float*)(ws + 89477120);                    // 178,954,240 B
  u16*   Wcat  = (u16*)(ws + 89477120 + 178954240);          // 384*256*2
  u16*   Wfxb  = Wcat + 384 * 256;
  u16*   Wfhb  = Wfxb + 128 * 128;

  prep_weights<<<512, 256, 0, stream>>>(Wix, Wih, Wfx, Wfh, Wox, Woh, Wux, Wuh,
                                        Wcat, Wfxb, Wfhb);

  // level 7 (leaves): M=64/block, 8 waves
  leaf_kernel<<<262144 / 64, 512, 0, stream>>>(
      embeds, Wcat, bix, box, bux, h_all, c_all, 87376);

  // levels 6..0 (internal)
  for (int l = 6; l >= 0; --l) {
    int n = counts[l];
    int grid = (n + 31) / 32;
    level_kernel<<<grid, 256, 40960, stream>>>(
        embeds, Wcat, Wfxb, Wfhb, bix, bfx, box, bux,
        h_all, c_all, n, offsets[l], offsets[l + 1]);
  }

  out_kernel<<<1, 128, 0, stream>>>(h_all, Wout, bout, (float*)d_out);
}